// Round 2
// baseline (363.783 us; speedup 1.0000x reference)
//
#include <hip/hip_runtime.h>

// TemporalPatternDecoupling: level-1 db4 DWT low-pass reconstruction + residual.
// Verified index algebra (R1 passed):
//   ca[n]  = sum_{m=0..7} dec_lo[m] * x[sym(2n+1-m)]          n in [0, 2051)
//   t even: low[t] = d1*ca[t/2]     + d3*ca[t/2+1]     + d5*ca[t/2+2]     + d7*ca[t/2+3]
//   t odd : low[t] = d0*ca[(t-1)/2] + d2*ca[(t-1)/2+1] + d4*ca[(t-1)/2+2] + d6*ca[(t-1)/2+3]
//   high = x - low
//
// Structure: fully register-local, no LDS, no barriers. Thread owns outputs
// t = 8i..8i+7  ->  needs ca[4i..4i+6]  ->  needs x[8i-6..8i+13], covered by
// 6 aligned float4 loads of x[8i-8..8i+15]. Only i==0 / i==511 per row need
// symmetric reflection (scalar gather path for those 2 threads/row).
//
// R4 = R3 with the nontemporal builtin fixed: __builtin_nontemporal_store
// requires a clang-native vector type, not HIP's float4 class. Same codegen
// intent: global_store_dwordx4 with nt bit; outputs (268 MB, write-once) skip
// L2/L3, preserving cache residency for the input's 3x short-range reuse.

constexpr int L = 4096;   // row length (fixed by the problem)

typedef float v4f __attribute__((ext_vector_type(4)));

__global__ __launch_bounds__(256) void dwt_lowhigh(const float* __restrict__ x,
                                                   float* __restrict__ out,
                                                   int rows) {
    constexpr float d0 = -0.010597401784997278f;
    constexpr float d1 =  0.032883011666982945f;
    constexpr float d2 =  0.030841381835986965f;
    constexpr float d3 = -0.18703481171888114f;
    constexpr float d4 = -0.02798376941698385f;
    constexpr float d5 =  0.6308807679295904f;
    constexpr float d6 =  0.7148465705525415f;
    constexpr float d7 =  0.23037781330885523f;
    constexpr float DLO[8] = {d0, d1, d2, d3, d4, d5, d6, d7};

    const int gid = blockIdx.x * 256 + threadIdx.x;
    const int row = gid >> 9;        // 512 threads per row (8 outputs each)
    const int i   = gid & 511;
    const float* __restrict__ xr = x + (size_t)row * L;

    // xa[k] = x[8i-8+k], k = 0..23 (with symmetric reflection at row edges)
    float xa[24];
    const int b = 8 * i - 8;
    if (i >= 1 && i <= 510) {
        const v4f* __restrict__ x4 = (const v4f*)(xr + b);  // 32B-aligned
        #pragma unroll
        for (int k = 0; k < 6; ++k) {
            const v4f v = x4[k];
            xa[4 * k + 0] = v.x;
            xa[4 * k + 1] = v.y;
            xa[4 * k + 2] = v.z;
            xa[4 * k + 3] = v.w;
        }
    } else {
        #pragma unroll
        for (int k = 0; k < 24; ++k) {
            int j = b + k;
            j = (j < 0) ? (-1 - j) : ((j >= L) ? (2 * L - 1 - j) : j);
            xa[k] = xr[j];
        }
    }

    // ca[q] = ca[4i+q] = sum_m DLO[m] * xa[9 + 2q - m],  q = 0..6
    float ca[7];
    #pragma unroll
    for (int q = 0; q < 7; ++q) {
        float acc = 0.f;
        #pragma unroll
        for (int m = 0; m < 8; ++m) acc += DLO[m] * xa[9 + 2 * q - m];
        ca[q] = acc;
    }

    // low for t = 8i+2p (even) and 8i+2p+1 (odd), p = 0..3; base coeff = ca[p]
    float lo[8];
    #pragma unroll
    for (int p = 0; p < 4; ++p) {
        lo[2 * p]     = d1 * ca[p] + d3 * ca[p + 1] + d5 * ca[p + 2] + d7 * ca[p + 3];
        lo[2 * p + 1] = d0 * ca[p] + d2 * ca[p + 1] + d4 * ca[p + 2] + d6 * ca[p + 3];
    }

    float* __restrict__ lowr  = out + (size_t)row * L + 8 * i;
    float* __restrict__ highr = out + (size_t)rows * L + (size_t)row * L + 8 * i;
    v4f* l4 = (v4f*)lowr;
    v4f* h4 = (v4f*)highr;
    v4f lo0 = {lo[0], lo[1], lo[2], lo[3]};
    v4f lo1 = {lo[4], lo[5], lo[6], lo[7]};
    v4f hi0 = {xa[8]  - lo[0], xa[9]  - lo[1], xa[10] - lo[2], xa[11] - lo[3]};
    v4f hi1 = {xa[12] - lo[4], xa[13] - lo[5], xa[14] - lo[6], xa[15] - lo[7]};
    // Nontemporal: outputs are write-once, never re-read -> don't pollute L2/L3.
    __builtin_nontemporal_store(lo0, l4 + 0);
    __builtin_nontemporal_store(lo1, l4 + 1);
    __builtin_nontemporal_store(hi0, h4 + 0);
    __builtin_nontemporal_store(hi1, h4 + 1);
}

extern "C" void kernel_launch(void* const* d_in, const int* in_sizes, int n_in,
                              void* d_out, int out_size, void* d_ws, size_t ws_size,
                              hipStream_t stream) {
    const float* x = (const float*)d_in[0];
    float* out = (float*)d_out;
    const int rows = in_sizes[0] / L;                 // 16*512 = 8192
    const int nthreads = rows * (L / 8);              // 8 outputs per thread
    dwt_lowhigh<<<nthreads / 256, 256, 0, stream>>>(x, out, rows);
}

// Round 3
// 356.835 us; speedup vs baseline: 1.0195x; 1.0195x over previous
//
#include <hip/hip_runtime.h>

// TemporalPatternDecoupling: level-1 db4 DWT low-pass reconstruction + residual.
// Verified index algebra (R1 passed):
//   ca[n]  = sum_{m=0..7} dec_lo[m] * x[sym(2n+1-m)]          n in [0, 2051)
//   t even: low[t] = d1*ca[t/2]     + d3*ca[t/2+1]     + d5*ca[t/2+2]     + d7*ca[t/2+3]
//   t odd : low[t] = d0*ca[(t-1)/2] + d2*ca[(t-1)/2+1] + d4*ca[(t-1)/2+2] + d6*ca[(t-1)/2+3]
//   high = x - low
//
// Structure: fully register-local, no LDS, no barriers. Thread owns outputs
// t = 8i..8i+7  ->  needs ca[4i..4i+6]  ->  needs x[8i-6..8i+13], covered by
// 6 aligned float4 loads of x[8i-8..8i+15]. Only i==0 / i==511 per row need
// symmetric reflection (scalar gather path for those 2 threads/row).
//
// R5: REVERT the R4 nontemporal stores (356.4 -> 363.8 us regression).
// rocprof showed the timed region is dominated by ~2x168us harness poison
// fills (1.074 GB each @ 6.4 TB/s); the kernel itself runs <166us (likely
// ~26us, L3-backed). NT's evict-early policy reduced L2/L3 write absorption
// inside the kernel window -> slower. Plain cached stores are optimal here.

constexpr int L = 4096;   // row length (fixed by the problem)

__global__ __launch_bounds__(256) void dwt_lowhigh(const float* __restrict__ x,
                                                   float* __restrict__ out,
                                                   int rows) {
    constexpr float d0 = -0.010597401784997278f;
    constexpr float d1 =  0.032883011666982945f;
    constexpr float d2 =  0.030841381835986965f;
    constexpr float d3 = -0.18703481171888114f;
    constexpr float d4 = -0.02798376941698385f;
    constexpr float d5 =  0.6308807679295904f;
    constexpr float d6 =  0.7148465705525415f;
    constexpr float d7 =  0.23037781330885523f;
    constexpr float DLO[8] = {d0, d1, d2, d3, d4, d5, d6, d7};

    const int gid = blockIdx.x * 256 + threadIdx.x;
    const int row = gid >> 9;        // 512 threads per row (8 outputs each)
    const int i   = gid & 511;
    const float* __restrict__ xr = x + (size_t)row * L;

    // xa[k] = x[8i-8+k], k = 0..23 (with symmetric reflection at row edges)
    float xa[24];
    const int b = 8 * i - 8;
    if (i >= 1 && i <= 510) {
        const float4* __restrict__ x4 = (const float4*)(xr + b);  // 32B-aligned
        #pragma unroll
        for (int k = 0; k < 6; ++k) {
            const float4 v = x4[k];
            xa[4 * k + 0] = v.x;
            xa[4 * k + 1] = v.y;
            xa[4 * k + 2] = v.z;
            xa[4 * k + 3] = v.w;
        }
    } else {
        #pragma unroll
        for (int k = 0; k < 24; ++k) {
            int j = b + k;
            j = (j < 0) ? (-1 - j) : ((j >= L) ? (2 * L - 1 - j) : j);
            xa[k] = xr[j];
        }
    }

    // ca[q] = ca[4i+q] = sum_m DLO[m] * xa[9 + 2q - m],  q = 0..6
    float ca[7];
    #pragma unroll
    for (int q = 0; q < 7; ++q) {
        float acc = 0.f;
        #pragma unroll
        for (int m = 0; m < 8; ++m) acc += DLO[m] * xa[9 + 2 * q - m];
        ca[q] = acc;
    }

    // low for t = 8i+2p (even) and 8i+2p+1 (odd), p = 0..3; base coeff = ca[p]
    float lo[8];
    #pragma unroll
    for (int p = 0; p < 4; ++p) {
        lo[2 * p]     = d1 * ca[p] + d3 * ca[p + 1] + d5 * ca[p + 2] + d7 * ca[p + 3];
        lo[2 * p + 1] = d0 * ca[p] + d2 * ca[p + 1] + d4 * ca[p + 2] + d6 * ca[p + 3];
    }

    float* __restrict__ lowr  = out + (size_t)row * L + 8 * i;
    float* __restrict__ highr = out + (size_t)rows * L + (size_t)row * L + 8 * i;
    float4* l4 = (float4*)lowr;
    float4* h4 = (float4*)highr;
    l4[0] = make_float4(lo[0], lo[1], lo[2], lo[3]);
    l4[1] = make_float4(lo[4], lo[5], lo[6], lo[7]);
    h4[0] = make_float4(xa[8]  - lo[0], xa[9]  - lo[1], xa[10] - lo[2], xa[11] - lo[3]);
    h4[1] = make_float4(xa[12] - lo[4], xa[13] - lo[5], xa[14] - lo[6], xa[15] - lo[7]);
}

extern "C" void kernel_launch(void* const* d_in, const int* in_sizes, int n_in,
                              void* d_out, int out_size, void* d_ws, size_t ws_size,
                              hipStream_t stream) {
    const float* x = (const float*)d_in[0];
    float* out = (float*)d_out;
    const int rows = in_sizes[0] / L;                 // 16*512 = 8192
    const int nthreads = rows * (L / 8);              // 8 outputs per thread
    dwt_lowhigh<<<nthreads / 256, 256, 0, stream>>>(x, out, rows);
}